// Round 8
// baseline (682.593 us; speedup 1.0000x reference)
//
#include <hip/hip_runtime.h>
#include <cmath>

// FAGCN: N=50000, E=1.6M, FEAT=512, HIDDEN=128, CLASS=40, 4 layers, eps=0.3
// R8: global-atomic-free CSR build. k_degree (memory-side atomic bound, ~21G
// atomics/s ceiling) replaced by per-chunk LDS 8-bit packed histograms
// (k_hist) + cross-chunk coalesced scan (k_hscan). csr_fill preloads its
// chunk's base row into LDS. Zero device-scope atomics in the whole pipeline.

#define HIDDEN 128
#define FEAT 512
#define NCLASS 40
#define LDST 40    // GEMM LDS row stride in ushorts (80 B)
#define NB 256     // histogram chunks (= blocks)
#define PITCH 12544  // words per partial row: 4 nodes/word -> supports N<=50176

typedef __attribute__((ext_vector_type(8))) short short8;
typedef __attribute__((ext_vector_type(4))) float f32x4;

__device__ __forceinline__ float bf_lo(unsigned u) { return __uint_as_float(u << 16); }
__device__ __forceinline__ float bf_hi(unsigned u) { return __uint_as_float(u & 0xffff0000u); }
__device__ __forceinline__ unsigned pack_bf16(float x, float y) {
    unsigned ux = __float_as_uint(x);
    unsigned uy = __float_as_uint(y);
    unsigned lx = (ux + 0x7fffu + ((ux >> 16) & 1u)) >> 16;
    unsigned hy = (uy + 0x7fffu + ((uy >> 16) & 1u)) & 0xffff0000u;
    return hy | lx;
}
__device__ __forceinline__ float fast_tanh(float x) {
    x = fminf(fmaxf(x, -15.f), 15.f);
    float e = __expf(2.f * x);
    return (e - 1.f) / (e + 1.f);
}

// ---------------- per-chunk LDS histogram (8-bit packed) + local rank ----------
__global__ __launch_bounds__(256) void k_hist(const int* __restrict__ ei, int E, int CE,
                                              unsigned* __restrict__ partial,
                                              ushort* __restrict__ lrank) {
    __shared__ unsigned lh[PITCH];
    const int b = blockIdx.x, tid = threadIdx.x;
    for (int w = tid; w < PITCH; w += 256) lh[w] = 0;
    __syncthreads();
    int e0 = b * CE, e1 = min(E, e0 + CE);
    for (int e = e0 + tid; e < e1; e += 256) {
        int dst = ei[E + e];
        int sh = (dst & 3) * 8;
        unsigned old = atomicAdd(&lh[dst >> 2], 1u << sh);
        lrank[e] = (ushort)((old >> sh) & 0xffu);
    }
    __syncthreads();
    unsigned* prow = partial + (size_t)b * PITCH;
    for (int w = tid; w < PITCH; w += 256) prow[w] = lh[w];
}

// ---------------- cross-chunk exclusive scan (in place) + degree unpack --------
__global__ void k_hscan(unsigned* __restrict__ partial, int* __restrict__ deg, int n) {
    int w = blockIdx.x * 256 + threadIdx.x;
    if (w >= PITCH) return;
    unsigned run = 0;
    size_t idx = w;
    for (int b = 0; b < NB; ++b, idx += PITCH) {
        unsigned v = partial[idx];
        partial[idx] = run;   // exclusive base for chunk b (packed bytes)
        run += v;             // bytes never exceed 255 total -> no carry
    }
    int node = 4 * w;
    if (node < n)     deg[node]     = run & 0xffu;
    if (node + 1 < n) deg[node + 1] = (run >> 8) & 0xffu;
    if (node + 2 < n) deg[node + 2] = (run >> 16) & 0xffu;
    if (node + 3 < n) deg[node + 3] = run >> 24;
}

__global__ void k_dis(const int* __restrict__ deg, float* __restrict__ dis, int n) {
    int i = blockIdx.x * 256 + threadIdx.x;
    if (i < n) dis[i] = rsqrtf((float)(deg[i] + 1));
}

// ---------------- exclusive scan over node degrees (offs) ----------------
__global__ void k_scan1(const int* __restrict__ deg, int* __restrict__ offs,
                        int* __restrict__ part, int n) {
    __shared__ int s[256];
    int tid = threadIdx.x;
    int gid = blockIdx.x * 256 + tid;
    int v = (gid < n) ? deg[gid] : 0;
    s[tid] = v;
    __syncthreads();
    for (int off = 1; off < 256; off <<= 1) {
        int t = (tid >= off) ? s[tid - off] : 0;
        __syncthreads();
        s[tid] += t;
        __syncthreads();
    }
    if (gid < n) offs[gid] = s[tid] - v;
    if (tid == 255) part[blockIdx.x] = s[255];
}

__global__ void k_scan2(int* __restrict__ part, int nb) {
    __shared__ int s[256];
    int tid = threadIdx.x;
    int v = (tid < nb) ? part[tid] : 0;
    s[tid] = v;
    __syncthreads();
    for (int off = 1; off < 256; off <<= 1) {
        int t = (tid >= off) ? s[tid - off] : 0;
        __syncthreads();
        s[tid] += t;
        __syncthreads();
    }
    if (tid < nb) part[tid] = s[tid] - v;
}

__global__ void k_scan3(int* __restrict__ offs, const int* __restrict__ part, int n, int E) {
    int gid = blockIdx.x * 256 + threadIdx.x;
    if (gid < n) offs[gid] += part[blockIdx.x];
    if (gid == 0) offs[n] = E;
}

// ---------------- CSR fill: no atomics; chunk base row staged in LDS -----------
__global__ __launch_bounds__(256) void k_csr_fill(const int* __restrict__ ei, int E, int CE,
                                                  const int* __restrict__ offs,
                                                  const unsigned* __restrict__ partial,
                                                  const ushort* __restrict__ lrank,
                                                  int* __restrict__ csrc) {
    __shared__ unsigned lp[PITCH];
    const int b = blockIdx.x, tid = threadIdx.x;
    const unsigned* prow = partial + (size_t)b * PITCH;
    for (int w = tid; w < PITCH; w += 256) lp[w] = prow[w];
    __syncthreads();
    int e0 = b * CE, e1 = min(E, e0 + CE);
    for (int e = e0 + tid; e < e1; e += 256) {
        int dst = ei[E + e];
        int src = ei[e];
        unsigned wv = lp[dst >> 2];
        int base = (wv >> ((dst & 3) * 8)) & 0xffu;
        csrc[offs[dst] + base + (int)lrank[e]] = src;
    }
}

// ---------------- GEMM1: h = relu(x @ W1^T + b1), MFMA bf16 -------------------
__global__ __launch_bounds__(256) void k_gemm1(const float* __restrict__ x,
                                               const float* __restrict__ W1,
                                               const float* __restrict__ b1,
                                               float* __restrict__ h, int M) {
    __shared__ ushort As[128 * LDST];
    __shared__ ushort Bs[128 * LDST];
    const int tid = threadIdx.x;
    const int bm = blockIdx.x * 128;
    const int wave = tid >> 6, lane = tid & 63;
    const int rh = (wave >> 1) * 64;
    const int ch = (wave & 1) * 64;
    const int sub = lane & 15, quad = lane >> 4;
    const int lrow = tid >> 3;
    const int lcol = (tid & 7) * 4;
    f32x4 acc[4][4] = {};
    for (int k0 = 0; k0 < FEAT; k0 += 32) {
#pragma unroll
        for (int i = 0; i < 4; ++i) {
            int r = lrow + 32 * i;
            int grow = bm + r;
            float4 v = make_float4(0.f, 0.f, 0.f, 0.f);
            if (grow < M) v = *(const float4*)(x + (size_t)grow * FEAT + k0 + lcol);
            uint2 pk = make_uint2(pack_bf16(v.x, v.y), pack_bf16(v.z, v.w));
            *(uint2*)(As + r * LDST + lcol) = pk;
        }
#pragma unroll
        for (int i = 0; i < 4; ++i) {
            int r = lrow + 32 * i;
            float4 v = *(const float4*)(W1 + (size_t)r * FEAT + k0 + lcol);
            uint2 pk = make_uint2(pack_bf16(v.x, v.y), pack_bf16(v.z, v.w));
            *(uint2*)(Bs + r * LDST + lcol) = pk;
        }
        __syncthreads();
        short8 af[4], bfr[4];
#pragma unroll
        for (int t = 0; t < 4; ++t)
            af[t] = *(const short8*)(As + (rh + t * 16 + sub) * LDST + quad * 8);
#pragma unroll
        for (int u = 0; u < 4; ++u)
            bfr[u] = *(const short8*)(Bs + (ch + u * 16 + sub) * LDST + quad * 8);
#pragma unroll
        for (int t = 0; t < 4; ++t)
#pragma unroll
            for (int u = 0; u < 4; ++u)
                acc[t][u] = __builtin_amdgcn_mfma_f32_16x16x32_bf16(af[t], bfr[u], acc[t][u], 0, 0, 0);
        __syncthreads();
    }
    float b1v[4];
#pragma unroll
    for (int u = 0; u < 4; ++u) b1v[u] = b1[ch + u * 16 + sub];
#pragma unroll
    for (int t = 0; t < 4; ++t) {
#pragma unroll
        for (int u = 0; u < 4; ++u) {
            int col = ch + u * 16 + sub;
#pragma unroll
            for (int r2 = 0; r2 < 4; ++r2) {
                int grow = bm + rh + t * 16 + quad * 4 + r2;
                if (grow < M)
                    h[(size_t)grow * HIDDEN + col] = fmaxf(acc[t][u][r2] + b1v[u], 0.f);
            }
        }
    }
}

// ---------------- prep: bf16 pack + layer-0 dots -> {al,dis}, ar ----------------
__global__ void k_prep(const float* __restrict__ h, unsigned* __restrict__ hbf,
                       const float* __restrict__ attl, const float* __restrict__ attr,
                       const float* __restrict__ dis, float2* __restrict__ al2,
                       float* __restrict__ ar, int n) {
    int node = (blockIdx.x * blockDim.x + threadIdx.x) >> 6;
    int lane = threadIdx.x & 63;
    if (node >= n) return;
    float2 hv = ((const float2*)(h + (size_t)node * HIDDEN))[lane];
    hbf[(size_t)node * 64 + lane] = pack_bf16(hv.x, hv.y);
    float pl = hv.x * attl[2 * lane] + hv.y * attl[2 * lane + 1];
    float pr = hv.x * attr[2 * lane] + hv.y * attr[2 * lane + 1];
    for (int off = 32; off; off >>= 1) {
        pl += __shfl_down(pl, off);
        pr += __shfl_down(pr, off);
    }
    if (lane == 0) {
        al2[node] = make_float2(pl, dis[node]);
        ar[node] = pr;
    }
}

// ---------------- aggregate: coef computed once/edge, shuffled to groups --------
__global__ void k_aggregate(const unsigned* __restrict__ hbf, const float* __restrict__ raw,
                            const float2* __restrict__ al2, const float* __restrict__ ar,
                            const int* __restrict__ offs, const int* __restrict__ csrc,
                            float* __restrict__ hout, unsigned* __restrict__ houtbf,
                            const float* __restrict__ attl_n, const float* __restrict__ attr_n,
                            float2* __restrict__ al2_o, float* __restrict__ ar_o, int n) {
    int node = (blockIdx.x * blockDim.x + threadIdx.x) >> 6;
    int lane = threadIdx.x & 63;
    if (node >= n) return;
    const int grp = lane >> 4;
    const int sub = lane & 15;
    const float arn = ar[node];
    const float2 selfld = al2[node];
    const float disn = selfld.y;
    float acc[8] = {0.f, 0.f, 0.f, 0.f, 0.f, 0.f, 0.f, 0.f};
    int e0 = offs[node], e1 = offs[node + 1];
    int e = e0;
    for (; e + 16 <= e1; e += 16) {
        int smy = csrc[e + sub];
        float2 lmy = al2[smy];
        float cmy = fast_tanh(lmy.x + arn) * lmy.y * disn;
        int sa = __shfl(smy, grp);
        int sb = __shfl(smy, 4 + grp);
        int sc = __shfl(smy, 8 + grp);
        int sd = __shfl(smy, 12 + grp);
        float ca = __shfl(cmy, grp);
        float cb = __shfl(cmy, 4 + grp);
        float cc = __shfl(cmy, 8 + grp);
        float cd = __shfl(cmy, 12 + grp);
        uint4 ra = *(const uint4*)(hbf + (size_t)sa * 64 + sub * 4);
        uint4 rb = *(const uint4*)(hbf + (size_t)sb * 64 + sub * 4);
        uint4 rc = *(const uint4*)(hbf + (size_t)sc * 64 + sub * 4);
        uint4 rd = *(const uint4*)(hbf + (size_t)sd * 64 + sub * 4);
        acc[0] += ca * bf_lo(ra.x); acc[1] += ca * bf_hi(ra.x);
        acc[2] += ca * bf_lo(ra.y); acc[3] += ca * bf_hi(ra.y);
        acc[4] += ca * bf_lo(ra.z); acc[5] += ca * bf_hi(ra.z);
        acc[6] += ca * bf_lo(ra.w); acc[7] += ca * bf_hi(ra.w);
        acc[0] += cb * bf_lo(rb.x); acc[1] += cb * bf_hi(rb.x);
        acc[2] += cb * bf_lo(rb.y); acc[3] += cb * bf_hi(rb.y);
        acc[4] += cb * bf_lo(rb.z); acc[5] += cb * bf_hi(rb.z);
        acc[6] += cb * bf_lo(rb.w); acc[7] += cb * bf_hi(rb.w);
        acc[0] += cc * bf_lo(rc.x); acc[1] += cc * bf_hi(rc.x);
        acc[2] += cc * bf_lo(rc.y); acc[3] += cc * bf_hi(rc.y);
        acc[4] += cc * bf_lo(rc.z); acc[5] += cc * bf_hi(rc.z);
        acc[6] += cc * bf_lo(rc.w); acc[7] += cc * bf_hi(rc.w);
        acc[0] += cd * bf_lo(rd.x); acc[1] += cd * bf_hi(rd.x);
        acc[2] += cd * bf_lo(rd.y); acc[3] += cd * bf_hi(rd.y);
        acc[4] += cd * bf_lo(rd.z); acc[5] += cd * bf_hi(rd.z);
        acc[6] += cd * bf_lo(rd.w); acc[7] += cd * bf_hi(rd.w);
    }
    for (; e + 4 <= e1; e += 4) {
        int sa = csrc[e + grp];
        float2 la = al2[sa];
        uint4 ra = *(const uint4*)(hbf + (size_t)sa * 64 + sub * 4);
        float ca = fast_tanh(la.x + arn) * la.y * disn;
        acc[0] += ca * bf_lo(ra.x); acc[1] += ca * bf_hi(ra.x);
        acc[2] += ca * bf_lo(ra.y); acc[3] += ca * bf_hi(ra.y);
        acc[4] += ca * bf_lo(ra.z); acc[5] += ca * bf_hi(ra.z);
        acc[6] += ca * bf_lo(ra.w); acc[7] += ca * bf_hi(ra.w);
    }
#pragma unroll
    for (int j = 0; j < 8; ++j) {
        acc[j] += __shfl_xor(acc[j], 16);
        acc[j] += __shfl_xor(acc[j], 32);
    }
    for (; e < e1; ++e) {
        int s = csrc[e];
        float2 ls = al2[s];
        uint4 r = *(const uint4*)(hbf + (size_t)s * 64 + sub * 4);
        float c = fast_tanh(ls.x + arn) * ls.y * disn;
        acc[0] += c * bf_lo(r.x); acc[1] += c * bf_hi(r.x);
        acc[2] += c * bf_lo(r.y); acc[3] += c * bf_hi(r.y);
        acc[4] += c * bf_lo(r.z); acc[5] += c * bf_hi(r.z);
        acc[6] += c * bf_lo(r.w); acc[7] += c * bf_hi(r.w);
    }
    {
        float c = fast_tanh(selfld.x + arn) * disn * disn;
        uint4 r = *(const uint4*)(hbf + (size_t)node * 64 + sub * 4);
        acc[0] += c * bf_lo(r.x); acc[1] += c * bf_hi(r.x);
        acc[2] += c * bf_lo(r.y); acc[3] += c * bf_hi(r.y);
        acc[4] += c * bf_lo(r.z); acc[5] += c * bf_hi(r.z);
        acc[6] += c * bf_lo(r.w); acc[7] += c * bf_hi(r.w);
    }
    float o[8];
    {
        float4 rv0 = *(const float4*)(raw + (size_t)node * HIDDEN + sub * 8);
        float4 rv1 = *(const float4*)(raw + (size_t)node * HIDDEN + sub * 8 + 4);
        o[0] = acc[0] + 0.3f * rv0.x; o[1] = acc[1] + 0.3f * rv0.y;
        o[2] = acc[2] + 0.3f * rv0.z; o[3] = acc[3] + 0.3f * rv0.w;
        o[4] = acc[4] + 0.3f * rv1.x; o[5] = acc[5] + 0.3f * rv1.y;
        o[6] = acc[6] + 0.3f * rv1.z; o[7] = acc[7] + 0.3f * rv1.w;
    }
    if (grp == 0) {
        *(float4*)(hout + (size_t)node * HIDDEN + sub * 8) = make_float4(o[0], o[1], o[2], o[3]);
        *(float4*)(hout + (size_t)node * HIDDEN + sub * 8 + 4) = make_float4(o[4], o[5], o[6], o[7]);
        if (houtbf) {
            uint4 pk = make_uint4(pack_bf16(o[0], o[1]), pack_bf16(o[2], o[3]),
                                  pack_bf16(o[4], o[5]), pack_bf16(o[6], o[7]));
            *(uint4*)(houtbf + (size_t)node * 64 + sub * 4) = pk;
        }
    }
    if (attl_n) {
        float4 a0 = *(const float4*)(attl_n + sub * 8);
        float4 a1 = *(const float4*)(attl_n + sub * 8 + 4);
        float4 c0 = *(const float4*)(attr_n + sub * 8);
        float4 c1 = *(const float4*)(attr_n + sub * 8 + 4);
        float pl = o[0] * a0.x + o[1] * a0.y + o[2] * a0.z + o[3] * a0.w +
                   o[4] * a1.x + o[5] * a1.y + o[6] * a1.z + o[7] * a1.w;
        float pr = o[0] * c0.x + o[1] * c0.y + o[2] * c0.z + o[3] * c0.w +
                   o[4] * c1.x + o[5] * c1.y + o[6] * c1.z + o[7] * c1.w;
        for (int off = 8; off; off >>= 1) {
            pl += __shfl_xor(pl, off);
            pr += __shfl_xor(pr, off);
        }
        if (lane == 0) {
            al2_o[node] = make_float2(pl, disn);
            ar_o[node] = pr;
        }
    }
}

// ---------------- output: log_softmax(h @ W2^T + b2) ---------------------------
__global__ __launch_bounds__(256) void k_out(const float* __restrict__ h,
                                             const float* __restrict__ W2,
                                             const float* __restrict__ b2,
                                             float* __restrict__ out, int n) {
    __shared__ float ws[NCLASS * HIDDEN];
    __shared__ float bs[NCLASS];
    const int tid = threadIdx.x;
    for (int i = tid; i < NCLASS * HIDDEN / 4; i += 256)
        ((float4*)ws)[i] = ((const float4*)W2)[i];
    if (tid < NCLASS) bs[tid] = b2[tid];
    __syncthreads();
    int node = blockIdx.x * 256 + tid;
    if (node >= n) return;
    const float* hr = h + (size_t)node * HIDDEN;
    float acc[NCLASS];
#pragma unroll
    for (int c = 0; c < NCLASS; ++c) acc[c] = bs[c];
#pragma unroll
    for (int k0 = 0; k0 < HIDDEN; k0 += 16) {
        float4 h0 = *(const float4*)(hr + k0);
        float4 h1 = *(const float4*)(hr + k0 + 4);
        float4 h2 = *(const float4*)(hr + k0 + 8);
        float4 h3 = *(const float4*)(hr + k0 + 12);
#pragma unroll
        for (int c = 0; c < NCLASS; ++c) {
            const float* w = ws + c * HIDDEN + k0;
            float4 w0 = *(const float4*)(w);
            float4 w1 = *(const float4*)(w + 4);
            float4 w2v = *(const float4*)(w + 8);
            float4 w3 = *(const float4*)(w + 12);
            acc[c] += h0.x * w0.x + h0.y * w0.y + h0.z * w0.z + h0.w * w0.w +
                      h1.x * w1.x + h1.y * w1.y + h1.z * w1.z + h1.w * w1.w +
                      h2.x * w2v.x + h2.y * w2v.y + h2.z * w2v.z + h2.w * w2v.w +
                      h3.x * w3.x + h3.y * w3.y + h3.z * w3.z + h3.w * w3.w;
        }
    }
    float m = -INFINITY;
#pragma unroll
    for (int c = 0; c < NCLASS; ++c) m = fmaxf(m, acc[c]);
    float ssum = 0.f;
#pragma unroll
    for (int c = 0; c < NCLASS; ++c) ssum += expf(acc[c] - m);
    float lse = m + logf(ssum);
    float* orow = out + (size_t)node * NCLASS;
#pragma unroll
    for (int c = 0; c < NCLASS; ++c) orow[c] = acc[c] - lse;
}

extern "C" void kernel_launch(void* const* d_in, const int* in_sizes, int n_in,
                              void* d_out, int out_size, void* d_ws, size_t ws_size,
                              hipStream_t stream) {
    const float* x    = (const float*)d_in[0];
    const int*   ei   = (const int*)d_in[1];
    const float* W1   = (const float*)d_in[2];
    const float* b1   = (const float*)d_in[3];
    const float* W2   = (const float*)d_in[4];
    const float* b2   = (const float*)d_in[5];
    const float* attl = (const float*)d_in[6];
    const float* attr = (const float*)d_in[7];
    const int N = in_sizes[0] / FEAT;
    const int E = in_sizes[1] / 2;
    float* out = (float*)d_out;

    char* p = (char*)d_ws;
    auto take = [&](size_t bytes) {
        void* q = (void*)p;
        p += (bytes + 255) & ~(size_t)255;
        return q;
    };
    float*    h0   = (float*)take((size_t)N * HIDDEN * 4);  // = raw
    float*    h1   = (float*)take((size_t)N * HIDDEN * 4);
    float*    h2   = (float*)take((size_t)N * HIDDEN * 4);
    unsigned* hb0  = (unsigned*)take((size_t)N * 64 * 4);
    unsigned* hb1  = (unsigned*)take((size_t)N * 64 * 4);
    int*      deg  = (int*)take((size_t)N * 4);
    float*    dis  = (float*)take((size_t)N * 4);
    int*      offs = (int*)take((size_t)(N + 1) * 4);
    unsigned* partial = (unsigned*)take((size_t)NB * PITCH * 4);
    ushort*   lrank   = (ushort*)take((size_t)E * 2);
    int*      csrc = (int*)take((size_t)E * 4);
    float2*   al2A = (float2*)take((size_t)N * 8);
    float2*   al2B = (float2*)take((size_t)N * 8);
    float*    arA  = (float*)take((size_t)N * 4);
    float*    arB  = (float*)take((size_t)N * 4);
    int*      part = (int*)take(1024);

    const int nbl = (N + 255) / 256;
    const int CE = (E + NB - 1) / NB;

    k_hist<<<NB, 256, 0, stream>>>(ei, E, CE, partial, lrank);
    k_hscan<<<(PITCH + 255) / 256, 256, 0, stream>>>(partial, deg, N);
    k_dis<<<nbl, 256, 0, stream>>>(deg, dis, N);
    k_scan1<<<nbl, 256, 0, stream>>>(deg, offs, part, N);
    k_scan2<<<1, 256, 0, stream>>>(part, nbl);
    k_scan3<<<nbl, 256, 0, stream>>>(offs, part, N, E);
    k_csr_fill<<<NB, 256, 0, stream>>>(ei, E, CE, offs, partial, lrank, csrc);

    k_gemm1<<<(N + 127) / 128, 256, 0, stream>>>(x, W1, b1, h0, N);
    k_prep<<<(N + 3) / 4, 256, 0, stream>>>(h0, hb0, attl, attr, dis, al2A, arA, N);

    float*    fout[4] = {h1, h2, h1, h2};
    unsigned* hbin = hb0, *hbout = hb1;
    float2*   alin = al2A, *alout = al2B;
    float*    arin = arA,  *arout = arB;
    for (int l = 0; l < 4; ++l) {
        const float* attl_n = (l < 3) ? (attl + (l + 1) * HIDDEN) : nullptr;
        const float* attr_n = (l < 3) ? (attr + (l + 1) * HIDDEN) : nullptr;
        unsigned* hbo = (l < 3) ? hbout : nullptr;
        k_aggregate<<<(N + 3) / 4, 256, 0, stream>>>(hbin, h0, alin, arin, offs, csrc,
                                                     fout[l], hbo, attl_n, attr_n,
                                                     alout, arout, N);
        unsigned* tb = hbin; hbin = hbout; hbout = tb;
        float2* ta = alin; alin = alout; alout = ta;
        float* tr = arin; arin = arout; arout = tr;
    }

    k_out<<<(N + 255) / 256, 256, 0, stream>>>(h2, W2, b2, out, N);
}

// Round 9
// 578.656 us; speedup vs baseline: 1.1796x; 1.1796x over previous
//
#include <hip/hip_runtime.h>
#include <cmath>

// FAGCN: N=50000, E=1.6M, FEAT=512, HIDDEN=128, CLASS=40, 4 layers, eps=0.3
// R9: k_out restructured — 2 lanes per node (20 classes each, shfl_xor(1)
// softmax combine), grid 391 blocks instead of 196, acc[20] instead of acc[40]
// (VGPR 132 -> ~70). Fixes the 1-wave-per-SIMD stall machine seen in R8
// (154 us, 8.9% occupancy, VALUBusy 6%). Rest unchanged from R8.

#define HIDDEN 128
#define FEAT 512
#define NCLASS 40
#define LDST 40    // GEMM LDS row stride in ushorts (80 B)
#define NB 256     // histogram chunks (= blocks)
#define PITCH 12544  // words per partial row: 4 nodes/word -> supports N<=50176

typedef __attribute__((ext_vector_type(8))) short short8;
typedef __attribute__((ext_vector_type(4))) float f32x4;

__device__ __forceinline__ float bf_lo(unsigned u) { return __uint_as_float(u << 16); }
__device__ __forceinline__ float bf_hi(unsigned u) { return __uint_as_float(u & 0xffff0000u); }
__device__ __forceinline__ unsigned pack_bf16(float x, float y) {
    unsigned ux = __float_as_uint(x);
    unsigned uy = __float_as_uint(y);
    unsigned lx = (ux + 0x7fffu + ((ux >> 16) & 1u)) >> 16;
    unsigned hy = (uy + 0x7fffu + ((uy >> 16) & 1u)) & 0xffff0000u;
    return hy | lx;
}
__device__ __forceinline__ float fast_tanh(float x) {
    x = fminf(fmaxf(x, -15.f), 15.f);
    float e = __expf(2.f * x);
    return (e - 1.f) / (e + 1.f);
}

// ---------------- per-chunk LDS histogram (8-bit packed) + local rank ----------
__global__ __launch_bounds__(256) void k_hist(const int* __restrict__ ei, int E, int CE,
                                              unsigned* __restrict__ partial,
                                              ushort* __restrict__ lrank) {
    __shared__ unsigned lh[PITCH];
    const int b = blockIdx.x, tid = threadIdx.x;
    for (int w = tid; w < PITCH; w += 256) lh[w] = 0;
    __syncthreads();
    int e0 = b * CE, e1 = min(E, e0 + CE);
    for (int e = e0 + tid; e < e1; e += 256) {
        int dst = ei[E + e];
        int sh = (dst & 3) * 8;
        unsigned old = atomicAdd(&lh[dst >> 2], 1u << sh);
        lrank[e] = (ushort)((old >> sh) & 0xffu);
    }
    __syncthreads();
    unsigned* prow = partial + (size_t)b * PITCH;
    for (int w = tid; w < PITCH; w += 256) prow[w] = lh[w];
}

// ---------------- cross-chunk exclusive scan (in place) + degree unpack --------
__global__ void k_hscan(unsigned* __restrict__ partial, int* __restrict__ deg, int n) {
    int w = blockIdx.x * 256 + threadIdx.x;
    if (w >= PITCH) return;
    unsigned run = 0;
    size_t idx = w;
    for (int b = 0; b < NB; ++b, idx += PITCH) {
        unsigned v = partial[idx];
        partial[idx] = run;
        run += v;
    }
    int node = 4 * w;
    if (node < n)     deg[node]     = run & 0xffu;
    if (node + 1 < n) deg[node + 1] = (run >> 8) & 0xffu;
    if (node + 2 < n) deg[node + 2] = (run >> 16) & 0xffu;
    if (node + 3 < n) deg[node + 3] = run >> 24;
}

__global__ void k_dis(const int* __restrict__ deg, float* __restrict__ dis, int n) {
    int i = blockIdx.x * 256 + threadIdx.x;
    if (i < n) dis[i] = rsqrtf((float)(deg[i] + 1));
}

// ---------------- exclusive scan over node degrees (offs) ----------------
__global__ void k_scan1(const int* __restrict__ deg, int* __restrict__ offs,
                        int* __restrict__ part, int n) {
    __shared__ int s[256];
    int tid = threadIdx.x;
    int gid = blockIdx.x * 256 + tid;
    int v = (gid < n) ? deg[gid] : 0;
    s[tid] = v;
    __syncthreads();
    for (int off = 1; off < 256; off <<= 1) {
        int t = (tid >= off) ? s[tid - off] : 0;
        __syncthreads();
        s[tid] += t;
        __syncthreads();
    }
    if (gid < n) offs[gid] = s[tid] - v;
    if (tid == 255) part[blockIdx.x] = s[255];
}

__global__ void k_scan2(int* __restrict__ part, int nb) {
    __shared__ int s[256];
    int tid = threadIdx.x;
    int v = (tid < nb) ? part[tid] : 0;
    s[tid] = v;
    __syncthreads();
    for (int off = 1; off < 256; off <<= 1) {
        int t = (tid >= off) ? s[tid - off] : 0;
        __syncthreads();
        s[tid] += t;
        __syncthreads();
    }
    if (tid < nb) part[tid] = s[tid] - v;
}

__global__ void k_scan3(int* __restrict__ offs, const int* __restrict__ part, int n, int E) {
    int gid = blockIdx.x * 256 + threadIdx.x;
    if (gid < n) offs[gid] += part[blockIdx.x];
    if (gid == 0) offs[n] = E;
}

// ---------------- CSR fill: no atomics; chunk base row staged in LDS -----------
__global__ __launch_bounds__(256) void k_csr_fill(const int* __restrict__ ei, int E, int CE,
                                                  const int* __restrict__ offs,
                                                  const unsigned* __restrict__ partial,
                                                  const ushort* __restrict__ lrank,
                                                  int* __restrict__ csrc) {
    __shared__ unsigned lp[PITCH];
    const int b = blockIdx.x, tid = threadIdx.x;
    const unsigned* prow = partial + (size_t)b * PITCH;
    for (int w = tid; w < PITCH; w += 256) lp[w] = prow[w];
    __syncthreads();
    int e0 = b * CE, e1 = min(E, e0 + CE);
    for (int e = e0 + tid; e < e1; e += 256) {
        int dst = ei[E + e];
        int src = ei[e];
        unsigned wv = lp[dst >> 2];
        int base = (wv >> ((dst & 3) * 8)) & 0xffu;
        csrc[offs[dst] + base + (int)lrank[e]] = src;
    }
}

// ---------------- GEMM1: h = relu(x @ W1^T + b1), MFMA bf16 -------------------
__global__ __launch_bounds__(256) void k_gemm1(const float* __restrict__ x,
                                               const float* __restrict__ W1,
                                               const float* __restrict__ b1,
                                               float* __restrict__ h, int M) {
    __shared__ ushort As[128 * LDST];
    __shared__ ushort Bs[128 * LDST];
    const int tid = threadIdx.x;
    const int bm = blockIdx.x * 128;
    const int wave = tid >> 6, lane = tid & 63;
    const int rh = (wave >> 1) * 64;
    const int ch = (wave & 1) * 64;
    const int sub = lane & 15, quad = lane >> 4;
    const int lrow = tid >> 3;
    const int lcol = (tid & 7) * 4;
    f32x4 acc[4][4] = {};
    for (int k0 = 0; k0 < FEAT; k0 += 32) {
#pragma unroll
        for (int i = 0; i < 4; ++i) {
            int r = lrow + 32 * i;
            int grow = bm + r;
            float4 v = make_float4(0.f, 0.f, 0.f, 0.f);
            if (grow < M) v = *(const float4*)(x + (size_t)grow * FEAT + k0 + lcol);
            uint2 pk = make_uint2(pack_bf16(v.x, v.y), pack_bf16(v.z, v.w));
            *(uint2*)(As + r * LDST + lcol) = pk;
        }
#pragma unroll
        for (int i = 0; i < 4; ++i) {
            int r = lrow + 32 * i;
            float4 v = *(const float4*)(W1 + (size_t)r * FEAT + k0 + lcol);
            uint2 pk = make_uint2(pack_bf16(v.x, v.y), pack_bf16(v.z, v.w));
            *(uint2*)(Bs + r * LDST + lcol) = pk;
        }
        __syncthreads();
        short8 af[4], bfr[4];
#pragma unroll
        for (int t = 0; t < 4; ++t)
            af[t] = *(const short8*)(As + (rh + t * 16 + sub) * LDST + quad * 8);
#pragma unroll
        for (int u = 0; u < 4; ++u)
            bfr[u] = *(const short8*)(Bs + (ch + u * 16 + sub) * LDST + quad * 8);
#pragma unroll
        for (int t = 0; t < 4; ++t)
#pragma unroll
            for (int u = 0; u < 4; ++u)
                acc[t][u] = __builtin_amdgcn_mfma_f32_16x16x32_bf16(af[t], bfr[u], acc[t][u], 0, 0, 0);
        __syncthreads();
    }
    float b1v[4];
#pragma unroll
    for (int u = 0; u < 4; ++u) b1v[u] = b1[ch + u * 16 + sub];
#pragma unroll
    for (int t = 0; t < 4; ++t) {
#pragma unroll
        for (int u = 0; u < 4; ++u) {
            int col = ch + u * 16 + sub;
#pragma unroll
            for (int r2 = 0; r2 < 4; ++r2) {
                int grow = bm + rh + t * 16 + quad * 4 + r2;
                if (grow < M)
                    h[(size_t)grow * HIDDEN + col] = fmaxf(acc[t][u][r2] + b1v[u], 0.f);
            }
        }
    }
}

// ---------------- prep: bf16 pack + layer-0 dots -> {al,dis}, ar ----------------
__global__ void k_prep(const float* __restrict__ h, unsigned* __restrict__ hbf,
                       const float* __restrict__ attl, const float* __restrict__ attr,
                       const float* __restrict__ dis, float2* __restrict__ al2,
                       float* __restrict__ ar, int n) {
    int node = (blockIdx.x * blockDim.x + threadIdx.x) >> 6;
    int lane = threadIdx.x & 63;
    if (node >= n) return;
    float2 hv = ((const float2*)(h + (size_t)node * HIDDEN))[lane];
    hbf[(size_t)node * 64 + lane] = pack_bf16(hv.x, hv.y);
    float pl = hv.x * attl[2 * lane] + hv.y * attl[2 * lane + 1];
    float pr = hv.x * attr[2 * lane] + hv.y * attr[2 * lane + 1];
    for (int off = 32; off; off >>= 1) {
        pl += __shfl_down(pl, off);
        pr += __shfl_down(pr, off);
    }
    if (lane == 0) {
        al2[node] = make_float2(pl, dis[node]);
        ar[node] = pr;
    }
}

// ---------------- aggregate: coef computed once/edge, shuffled to groups --------
__global__ void k_aggregate(const unsigned* __restrict__ hbf, const float* __restrict__ raw,
                            const float2* __restrict__ al2, const float* __restrict__ ar,
                            const int* __restrict__ offs, const int* __restrict__ csrc,
                            float* __restrict__ hout, unsigned* __restrict__ houtbf,
                            const float* __restrict__ attl_n, const float* __restrict__ attr_n,
                            float2* __restrict__ al2_o, float* __restrict__ ar_o, int n) {
    int node = (blockIdx.x * blockDim.x + threadIdx.x) >> 6;
    int lane = threadIdx.x & 63;
    if (node >= n) return;
    const int grp = lane >> 4;
    const int sub = lane & 15;
    const float arn = ar[node];
    const float2 selfld = al2[node];
    const float disn = selfld.y;
    float acc[8] = {0.f, 0.f, 0.f, 0.f, 0.f, 0.f, 0.f, 0.f};
    int e0 = offs[node], e1 = offs[node + 1];
    int e = e0;
    for (; e + 16 <= e1; e += 16) {
        int smy = csrc[e + sub];
        float2 lmy = al2[smy];
        float cmy = fast_tanh(lmy.x + arn) * lmy.y * disn;
        int sa = __shfl(smy, grp);
        int sb = __shfl(smy, 4 + grp);
        int sc = __shfl(smy, 8 + grp);
        int sd = __shfl(smy, 12 + grp);
        float ca = __shfl(cmy, grp);
        float cb = __shfl(cmy, 4 + grp);
        float cc = __shfl(cmy, 8 + grp);
        float cd = __shfl(cmy, 12 + grp);
        uint4 ra = *(const uint4*)(hbf + (size_t)sa * 64 + sub * 4);
        uint4 rb = *(const uint4*)(hbf + (size_t)sb * 64 + sub * 4);
        uint4 rc = *(const uint4*)(hbf + (size_t)sc * 64 + sub * 4);
        uint4 rd = *(const uint4*)(hbf + (size_t)sd * 64 + sub * 4);
        acc[0] += ca * bf_lo(ra.x); acc[1] += ca * bf_hi(ra.x);
        acc[2] += ca * bf_lo(ra.y); acc[3] += ca * bf_hi(ra.y);
        acc[4] += ca * bf_lo(ra.z); acc[5] += ca * bf_hi(ra.z);
        acc[6] += ca * bf_lo(ra.w); acc[7] += ca * bf_hi(ra.w);
        acc[0] += cb * bf_lo(rb.x); acc[1] += cb * bf_hi(rb.x);
        acc[2] += cb * bf_lo(rb.y); acc[3] += cb * bf_hi(rb.y);
        acc[4] += cb * bf_lo(rb.z); acc[5] += cb * bf_hi(rb.z);
        acc[6] += cb * bf_lo(rb.w); acc[7] += cb * bf_hi(rb.w);
        acc[0] += cc * bf_lo(rc.x); acc[1] += cc * bf_hi(rc.x);
        acc[2] += cc * bf_lo(rc.y); acc[3] += cc * bf_hi(rc.y);
        acc[4] += cc * bf_lo(rc.z); acc[5] += cc * bf_hi(rc.z);
        acc[6] += cc * bf_lo(rc.w); acc[7] += cc * bf_hi(rc.w);
        acc[0] += cd * bf_lo(rd.x); acc[1] += cd * bf_hi(rd.x);
        acc[2] += cd * bf_lo(rd.y); acc[3] += cd * bf_hi(rd.y);
        acc[4] += cd * bf_lo(rd.z); acc[5] += cd * bf_hi(rd.z);
        acc[6] += cd * bf_lo(rd.w); acc[7] += cd * bf_hi(rd.w);
    }
    for (; e + 4 <= e1; e += 4) {
        int sa = csrc[e + grp];
        float2 la = al2[sa];
        uint4 ra = *(const uint4*)(hbf + (size_t)sa * 64 + sub * 4);
        float ca = fast_tanh(la.x + arn) * la.y * disn;
        acc[0] += ca * bf_lo(ra.x); acc[1] += ca * bf_hi(ra.x);
        acc[2] += ca * bf_lo(ra.y); acc[3] += ca * bf_hi(ra.y);
        acc[4] += ca * bf_lo(ra.z); acc[5] += ca * bf_hi(ra.z);
        acc[6] += ca * bf_lo(ra.w); acc[7] += ca * bf_hi(ra.w);
    }
#pragma unroll
    for (int j = 0; j < 8; ++j) {
        acc[j] += __shfl_xor(acc[j], 16);
        acc[j] += __shfl_xor(acc[j], 32);
    }
    for (; e < e1; ++e) {
        int s = csrc[e];
        float2 ls = al2[s];
        uint4 r = *(const uint4*)(hbf + (size_t)s * 64 + sub * 4);
        float c = fast_tanh(ls.x + arn) * ls.y * disn;
        acc[0] += c * bf_lo(r.x); acc[1] += c * bf_hi(r.x);
        acc[2] += c * bf_lo(r.y); acc[3] += c * bf_hi(r.y);
        acc[4] += c * bf_lo(r.z); acc[5] += c * bf_hi(r.z);
        acc[6] += c * bf_lo(r.w); acc[7] += c * bf_hi(r.w);
    }
    {
        float c = fast_tanh(selfld.x + arn) * disn * disn;
        uint4 r = *(const uint4*)(hbf + (size_t)node * 64 + sub * 4);
        acc[0] += c * bf_lo(r.x); acc[1] += c * bf_hi(r.x);
        acc[2] += c * bf_lo(r.y); acc[3] += c * bf_hi(r.y);
        acc[4] += c * bf_lo(r.z); acc[5] += c * bf_hi(r.z);
        acc[6] += c * bf_lo(r.w); acc[7] += c * bf_hi(r.w);
    }
    float o[8];
    {
        float4 rv0 = *(const float4*)(raw + (size_t)node * HIDDEN + sub * 8);
        float4 rv1 = *(const float4*)(raw + (size_t)node * HIDDEN + sub * 8 + 4);
        o[0] = acc[0] + 0.3f * rv0.x; o[1] = acc[1] + 0.3f * rv0.y;
        o[2] = acc[2] + 0.3f * rv0.z; o[3] = acc[3] + 0.3f * rv0.w;
        o[4] = acc[4] + 0.3f * rv1.x; o[5] = acc[5] + 0.3f * rv1.y;
        o[6] = acc[6] + 0.3f * rv1.z; o[7] = acc[7] + 0.3f * rv1.w;
    }
    if (grp == 0) {
        *(float4*)(hout + (size_t)node * HIDDEN + sub * 8) = make_float4(o[0], o[1], o[2], o[3]);
        *(float4*)(hout + (size_t)node * HIDDEN + sub * 8 + 4) = make_float4(o[4], o[5], o[6], o[7]);
        if (houtbf) {
            uint4 pk = make_uint4(pack_bf16(o[0], o[1]), pack_bf16(o[2], o[3]),
                                  pack_bf16(o[4], o[5]), pack_bf16(o[6], o[7]));
            *(uint4*)(houtbf + (size_t)node * 64 + sub * 4) = pk;
        }
    }
    if (attl_n) {
        float4 a0 = *(const float4*)(attl_n + sub * 8);
        float4 a1 = *(const float4*)(attl_n + sub * 8 + 4);
        float4 c0 = *(const float4*)(attr_n + sub * 8);
        float4 c1 = *(const float4*)(attr_n + sub * 8 + 4);
        float pl = o[0] * a0.x + o[1] * a0.y + o[2] * a0.z + o[3] * a0.w +
                   o[4] * a1.x + o[5] * a1.y + o[6] * a1.z + o[7] * a1.w;
        float pr = o[0] * c0.x + o[1] * c0.y + o[2] * c0.z + o[3] * c0.w +
                   o[4] * c1.x + o[5] * c1.y + o[6] * c1.z + o[7] * c1.w;
        for (int off = 8; off; off >>= 1) {
            pl += __shfl_xor(pl, off);
            pr += __shfl_xor(pr, off);
        }
        if (lane == 0) {
            al2_o[node] = make_float2(pl, disn);
            ar_o[node] = pr;
        }
    }
}

// ---------------- output: log_softmax(h @ W2^T + b2) ---------------------------
// 2 lanes per node: lane half=tid&1 computes classes [half*20, half*20+20);
// softmax combined via shfl_xor(1). Grid 391 blocks, acc[20] -> high occupancy.
__global__ __launch_bounds__(256) void k_out(const float* __restrict__ h,
                                             const float* __restrict__ W2,
                                             const float* __restrict__ b2,
                                             float* __restrict__ out, int n) {
    __shared__ float ws[NCLASS * HIDDEN];
    __shared__ float bs[NCLASS];
    const int tid = threadIdx.x;
    for (int i = tid; i < NCLASS * HIDDEN / 4; i += 256)
        ((float4*)ws)[i] = ((const float4*)W2)[i];
    if (tid < NCLASS) bs[tid] = b2[tid];
    __syncthreads();
    int node = blockIdx.x * 128 + (tid >> 1);
    const int half = tid & 1;
    const int c0 = half * 20;
    if (node >= n) return;
    const float* hr = h + (size_t)node * HIDDEN;
    float acc[20];
#pragma unroll
    for (int c = 0; c < 20; ++c) acc[c] = bs[c0 + c];
#pragma unroll
    for (int k0 = 0; k0 < HIDDEN; k0 += 16) {
        float4 h0 = *(const float4*)(hr + k0);
        float4 h1 = *(const float4*)(hr + k0 + 4);
        float4 h2v = *(const float4*)(hr + k0 + 8);
        float4 h3 = *(const float4*)(hr + k0 + 12);
#pragma unroll
        for (int c = 0; c < 20; ++c) {
            const float* w = ws + (c0 + c) * HIDDEN + k0;
            float4 w0 = *(const float4*)(w);
            float4 w1 = *(const float4*)(w + 4);
            float4 w2v = *(const float4*)(w + 8);
            float4 w3 = *(const float4*)(w + 12);
            acc[c] += h0.x * w0.x + h0.y * w0.y + h0.z * w0.z + h0.w * w0.w +
                      h1.x * w1.x + h1.y * w1.y + h1.z * w1.z + h1.w * w1.w +
                      h2v.x * w2v.x + h2v.y * w2v.y + h2v.z * w2v.z + h2v.w * w2v.w +
                      h3.x * w3.x + h3.y * w3.y + h3.z * w3.z + h3.w * w3.w;
        }
    }
    float m = -INFINITY;
#pragma unroll
    for (int c = 0; c < 20; ++c) m = fmaxf(m, acc[c]);
    m = fmaxf(m, __shfl_xor(m, 1));
    float ssum = 0.f;
#pragma unroll
    for (int c = 0; c < 20; ++c) ssum += expf(acc[c] - m);
    ssum += __shfl_xor(ssum, 1);
    float lse = m + logf(ssum);
    float* orow = out + (size_t)node * NCLASS + c0;
#pragma unroll
    for (int c = 0; c < 20; ++c) orow[c] = acc[c] - lse;
}

extern "C" void kernel_launch(void* const* d_in, const int* in_sizes, int n_in,
                              void* d_out, int out_size, void* d_ws, size_t ws_size,
                              hipStream_t stream) {
    const float* x    = (const float*)d_in[0];
    const int*   ei   = (const int*)d_in[1];
    const float* W1   = (const float*)d_in[2];
    const float* b1   = (const float*)d_in[3];
    const float* W2   = (const float*)d_in[4];
    const float* b2   = (const float*)d_in[5];
    const float* attl = (const float*)d_in[6];
    const float* attr = (const float*)d_in[7];
    const int N = in_sizes[0] / FEAT;
    const int E = in_sizes[1] / 2;
    float* out = (float*)d_out;

    char* p = (char*)d_ws;
    auto take = [&](size_t bytes) {
        void* q = (void*)p;
        p += (bytes + 255) & ~(size_t)255;
        return q;
    };
    float*    h0   = (float*)take((size_t)N * HIDDEN * 4);  // = raw
    float*    h1   = (float*)take((size_t)N * HIDDEN * 4);
    float*    h2   = (float*)take((size_t)N * HIDDEN * 4);
    unsigned* hb0  = (unsigned*)take((size_t)N * 64 * 4);
    unsigned* hb1  = (unsigned*)take((size_t)N * 64 * 4);
    int*      deg  = (int*)take((size_t)N * 4);
    float*    dis  = (float*)take((size_t)N * 4);
    int*      offs = (int*)take((size_t)(N + 1) * 4);
    unsigned* partial = (unsigned*)take((size_t)NB * PITCH * 4);
    ushort*   lrank   = (ushort*)take((size_t)E * 2);
    int*      csrc = (int*)take((size_t)E * 4);
    float2*   al2A = (float2*)take((size_t)N * 8);
    float2*   al2B = (float2*)take((size_t)N * 8);
    float*    arA  = (float*)take((size_t)N * 4);
    float*    arB  = (float*)take((size_t)N * 4);
    int*      part = (int*)take(1024);

    const int nbl = (N + 255) / 256;
    const int CE = (E + NB - 1) / NB;

    k_hist<<<NB, 256, 0, stream>>>(ei, E, CE, partial, lrank);
    k_hscan<<<(PITCH + 255) / 256, 256, 0, stream>>>(partial, deg, N);
    k_dis<<<nbl, 256, 0, stream>>>(deg, dis, N);
    k_scan1<<<nbl, 256, 0, stream>>>(deg, offs, part, N);
    k_scan2<<<1, 256, 0, stream>>>(part, nbl);
    k_scan3<<<nbl, 256, 0, stream>>>(offs, part, N, E);
    k_csr_fill<<<NB, 256, 0, stream>>>(ei, E, CE, offs, partial, lrank, csrc);

    k_gemm1<<<(N + 127) / 128, 256, 0, stream>>>(x, W1, b1, h0, N);
    k_prep<<<(N + 3) / 4, 256, 0, stream>>>(h0, hb0, attl, attr, dis, al2A, arA, N);

    float*    fout[4] = {h1, h2, h1, h2};
    unsigned* hbin = hb0, *hbout = hb1;
    float2*   alin = al2A, *alout = al2B;
    float*    arin = arA,  *arout = arB;
    for (int l = 0; l < 4; ++l) {
        const float* attl_n = (l < 3) ? (attl + (l + 1) * HIDDEN) : nullptr;
        const float* attr_n = (l < 3) ? (attr + (l + 1) * HIDDEN) : nullptr;
        unsigned* hbo = (l < 3) ? hbout : nullptr;
        k_aggregate<<<(N + 3) / 4, 256, 0, stream>>>(hbin, h0, alin, arin, offs, csrc,
                                                     fout[l], hbo, attl_n, attr_n,
                                                     alout, arout, N);
        unsigned* tb = hbin; hbin = hbout; hbout = tb;
        float2* ta = alin; alin = alout; alout = ta;
        float* tr = arin; arin = arout; arout = tr;
    }

    k_out<<<(N + 127) / 128, 256, 0, stream>>>(h2, W2, b2, out, N);
}